// Round 1
// baseline (414.507 us; speedup 1.0000x reference)
//
#include <hip/hip_runtime.h>
#include <math.h>

constexpr int B = 32, N = 1024, ND = 8, FEAT = 2048, WVD = 300;
constexpr int E = 20000, T = 2, STEPS = 5;
constexpr int NDIM = N * ND;            // 8192
constexpr int H1 = 512;
constexpr int W1C = FEAT + WVD;         // 2348
constexpr int EMB = 50;
constexpr int RC = EMB * ND * ND;       // 3200
constexpr int SROW = (STEPS + 1) * NDIM; // per-batch stride in states

// ---------------- CSR build ----------------
__global__ void k_hist(const int* eu, int* counts) {
    int i = blockIdx.x * 256 + threadIdx.x;
    if (i < T * E) {
        int t = i / E;
        atomicAdd(&counts[t * N + eu[i]], 1);
    }
}

__global__ void k_scan(const int* counts, int* ptr) {
    __shared__ int s0[2048], s1[2048];
    int tid = threadIdx.x;
    s0[tid] = counts[tid];
    s0[tid + 1024] = counts[tid + 1024];
    __syncthreads();
    int* src = s0; int* dst = s1;
    for (int st = 1; st < 2048; st <<= 1) {
        for (int j = tid; j < 2048; j += 1024)
            dst[j] = src[j] + (j >= st ? src[j - st] : 0);
        __syncthreads();
        int* tmp = src; src = dst; dst = tmp;
    }
    ptr[tid] = tid ? src[tid - 1] : 0;
    ptr[tid + 1024] = src[tid + 1023];
}

// deterministic scatter: one wave per (type,node), ballot-rank within row
__global__ void k_scatter(const int* eu, const int* ev, const int* ptr,
                          int* su, int* sv) {
    int wid = (blockIdx.x * blockDim.x + threadIdx.x) >> 6;
    int lane = threadIdx.x & 63;
    int t = wid >> 10, u = wid & (N - 1);
    const int* eut = eu + t * E;
    const int* evt = ev + t * E;
    int base = ptr[wid], cnt = 0;
    for (int c = 0; c < E; c += 64) {
        int e = c + lane;
        bool ok = (e < E) && (eut[e] == u);
        unsigned long long m = __ballot(ok);
        if (ok) {
            int rank = __popcll(m & ((1ull << lane) - 1));
            int pos = base + cnt + rank;
            su[pos] = u;
            sv[pos] = evt[e];
        }
        cnt += __popcll(m);
    }
}

// ---------------- inputnet ----------------
// A[b,c] = inputs[b,:2048] . W_in1[c,:2048]
__global__ void k_A(const float* inp, const float* W1, float* Ab) {
    int lane = threadIdx.x & 63;
    int w = threadIdx.x >> 6;
    int c = blockIdx.x * 4 + w;
    int b = blockIdx.y;
    const float* xr = inp + (size_t)b * FEAT;
    const float* wr = W1 + (size_t)c * W1C;
    float acc = 0.f;
#pragma unroll
    for (int i = 0; i < FEAT / 64; i++) {
        int k = i * 64 + lane;
        acc += xr[k] * wr[k];
    }
    for (int m = 32; m; m >>= 1) acc += __shfl_xor(acc, m, 64);
    if (lane == 0) Ab[b * H1 + c] = acc;
}

// Wv[n,c] = wordvecs[n,:300] . W_in1[c,2048:2348]   (wave computes 8 c's)
__global__ void k_Wv(const float* wv, const float* W1, float* Wvb) {
    int gw = (blockIdx.x * 256 + threadIdx.x) >> 6;
    int lane = threadIdx.x & 63;
    int n = gw >> 6;
    int c0 = (gw & 63) * 8;
    const float* xr = wv + (size_t)n * WVD;
    float acc[8] = {};
    for (int i = 0; i < 5; i++) {
        int k = i * 64 + lane;
        if (k < WVD) {
            float x = xr[k];
#pragma unroll
            for (int j = 0; j < 8; j++)
                acc[j] += x * W1[(size_t)(c0 + j) * W1C + FEAT + k];
        }
    }
#pragma unroll
    for (int j = 0; j < 8; j++)
        for (int m = 32; m; m >>= 1) acc[j] += __shfl_xor(acc[j], m, 64);
    if (lane == 0) {
#pragma unroll
        for (int j = 0; j < 8; j++) Wvb[n * H1 + c0 + j] = acc[j];
    }
}

// hidden0 = (relu(A[b]+Wv[n]+b1) @ W_in2^T + b2) -> states[:,0,:]
__global__ void k_inputnet(const float* Ab, const float* Wvb, const float* b1,
                           const float* W2, const float* b2, float* states) {
    int gw = (blockIdx.x * 256 + threadIdx.x) >> 6;
    int lane = threadIdx.x & 63;
    int b = gw >> 10, n = gw & (N - 1);
    const float* ar = Ab + b * H1;
    const float* vr = Wvb + n * H1;
    float acc[8] = {};
#pragma unroll
    for (int i = 0; i < H1 / 64; i++) {
        int c = i * 64 + lane;
        float t = ar[c] + vr[c] + b1[c];
        t = fmaxf(t, 0.f);
#pragma unroll
        for (int ki = 0; ki < 8; ki++) acc[ki] += t * W2[ki * H1 + c];
    }
#pragma unroll
    for (int ki = 0; ki < 8; ki++)
        for (int m = 32; m; m >>= 1) acc[ki] += __shfl_xor(acc[ki], m, 64);
    if (lane == 0) {
        float* o = states + (size_t)b * SROW + n * ND;
#pragma unroll
        for (int ki = 0; ki < 8; ki++) o[ki] = acc[ki] + b2[ki];
    }
}

// ---------------- relnet ----------------
__global__ void k_embs(const float* wv, const float* We, const float* be,
                       float* embs) {
    int i = blockIdx.x * 256 + threadIdx.x;
    int n = i >> 6, c = i & 63;
    if (c >= EMB) return;
    const float* xr = wv + (size_t)n * WVD;
    const float* wr = We + (size_t)c * WVD;
    float acc = be[c];
    for (int k = 0; k < WVD; k++) acc += xr[k] * wr[k];
    embs[n * EMB + c] = acc;
}

// Ahat[n, d*64+k] = sum_c embs[n,c] * RM[c, d*64+k]
__global__ void k_ahat(const float* embs, const float* RM, float* Ahat) {
    __shared__ float el[8][EMB];
    int tx = threadIdx.x;
    int n0 = blockIdx.y * 8;
    for (int i = tx; i < 8 * EMB; i += 256)
        el[i / EMB][i % EMB] = embs[(n0 + i / EMB) * EMB + i % EMB];
    __syncthreads();
    int m = blockIdx.x * 256 + tx;
    if (m >= RC) return;
    float acc[8] = {};
    for (int c = 0; c < EMB; c++) {
        float r = RM[(size_t)c * RC + m];
#pragma unroll
        for (int j = 0; j < 8; j++) acc[j] += el[j][c] * r;
    }
#pragma unroll
    for (int j = 0; j < 8; j++) Ahat[(size_t)(n0 + j) * RC + m] = acc[j];
}

// w[slot,k] = sum_d embs[v,d] * Ahat[u, d*64+k]   (one wave per edge slot)
__global__ void k_weights(const int* su, const int* sv, const float* embs,
                          const float* Ahat, float* wbuf, int slot0) {
    int wi = (blockIdx.x * 256 + threadIdx.x) >> 6;
    int k = threadIdx.x & 63;
    if (wi >= E) return;
    int slot = slot0 + wi;
    int u = su[slot], v = sv[slot];
    const float* ar = Ahat + (size_t)u * RC + k;
    const float* vr = embs + (size_t)v * EMB;
    float acc = 0.f;
#pragma unroll 10
    for (int d = 0; d < EMB; d++) acc += vr[d] * ar[d * 64];
    wbuf[(size_t)slot * 64 + k] = acc;
}

// norms[u*8+ki] = sqrt(sum over u's edges, kj of w^2); 0 -> 1  (deterministic)
__global__ void k_norms(const int* ptr, const int* counts, const float* wbuf,
                        float* norms) {
    int u = (blockIdx.x * 256 + threadIdx.x) >> 6;
    int lane = threadIdx.x & 63;
    int ki = lane >> 3, kj = lane & 7;
    float acc = 0.f;
    for (int t = 0; t < T; t++) {
        int base = ptr[t * N + u], c = counts[t * N + u];
        for (int i = 0; i < c; i++) {
            float x = wbuf[(size_t)(base + i) * 64 + lane];
            acc += x * x;
        }
    }
    acc += __shfl_xor(acc, 1, 64);
    acc += __shfl_xor(acc, 2, 64);
    acc += __shfl_xor(acc, 4, 64);
    if (kj == 0) {
        float nv = sqrtf(acc);
        if (nv == 0.f) nv = 1.f;
        norms[u * ND + ki] = nv;
    }
}

// w[slot, ki*8+kj] /= norms[v*8+kj]
__global__ void k_scale(const int* sv, float* wbuf, const float* norms) {
    int idx = blockIdx.x * 256 + threadIdx.x;
    int slot = idx >> 6, k = idx & 63;
    int v = sv[slot];
    wbuf[idx] = wbuf[idx] / norms[v * ND + (k & 7)];
}

// ---------------- propagation step: x = tanh(h @ P^T) fused with GRU ----------------
__global__ void k_step(const int* ptr, const int* counts, const int* sv,
                       const float* wbuf, float* states,
                       const float* W_ih, const float* W_hh,
                       const float* b_ih, const float* b_hh, int s) {
    __shared__ float wl[4][64];
    __shared__ int vl[4];
    __shared__ float xs[B][ND + 1];
    __shared__ float hsm[B][ND + 1];
    __shared__ float wih[24 * 8], whh[24 * 8];
    int tid = threadIdx.x;
    int u = blockIdx.x;
    int b = tid >> 3, ki = tid & 7;
    if (tid < 192) { wih[tid] = W_ih[tid]; whh[tid] = W_hh[tid]; }
    const float* hrow = states + ((size_t)(b * (STEPS + 1) + s)) * NDIM;
    float acc = 0.f;
    for (int t = 0; t < T; t++) {
        int base = ptr[t * N + u], cnt = counts[t * N + u];
        for (int c0 = 0; c0 < cnt; c0 += 4) {
            int nb = min(4, cnt - c0);
            __syncthreads();
            if (tid < nb * 64)
                wl[tid >> 6][tid & 63] =
                    wbuf[(size_t)(base + c0 + (tid >> 6)) * 64 + (tid & 63)];
            if (tid < nb) vl[tid] = sv[base + c0 + tid];
            __syncthreads();
            for (int j = 0; j < nb; j++) {
                int v = vl[j];
                const float4 h0 = *(const float4*)(hrow + v * ND);
                const float4 h1 = *(const float4*)(hrow + v * ND + 4);
                const float* wj = &wl[j][ki * 8];
                acc += h0.x * wj[0] + h0.y * wj[1] + h0.z * wj[2] + h0.w * wj[3]
                     + h1.x * wj[4] + h1.y * wj[5] + h1.z * wj[6] + h1.w * wj[7];
            }
        }
    }
    float xv = tanhf(acc);
    float hown = hrow[u * ND + ki];
    xs[b][ki] = xv;
    hsm[b][ki] = hown;
    __syncthreads();
    float gr = b_ih[ki], gz = b_ih[8 + ki], gn = b_ih[16 + ki];
    float hr = b_hh[ki], hz = b_hh[8 + ki], hn = b_hh[16 + ki];
#pragma unroll
    for (int j = 0; j < 8; j++) {
        float xj = xs[b][j], hj = hsm[b][j];
        gr += wih[ki * 8 + j] * xj;
        gz += wih[(8 + ki) * 8 + j] * xj;
        gn += wih[(16 + ki) * 8 + j] * xj;
        hr += whh[ki * 8 + j] * hj;
        hz += whh[(8 + ki) * 8 + j] * hj;
        hn += whh[(16 + ki) * 8 + j] * hj;
    }
    float r = 1.f / (1.f + expf(-(gr + hr)));
    float z = 1.f / (1.f + expf(-(gz + hz)));
    float nn = tanhf(gn + r * hn);
    float hnew = (1.f - z) * nn + z * hown;
    states[((size_t)(b * (STEPS + 1) + s + 1)) * NDIM + u * ND + ki] = hnew;
}

// ---------------- outnet ----------------
__global__ void k_out(const float* states, const float* Wo1, const float* bo1,
                      const float* Wo2, const float* bo2, float* out) {
    __shared__ float w1[160], bb1[20], w2[20];
    int tid = threadIdx.x;
    if (tid < 160) w1[tid] = Wo1[tid];
    if (tid < 20) { bb1[tid] = bo1[tid]; w2[tid] = Wo2[tid]; }
    __syncthreads();
    int i = blockIdx.x * 256 + tid;
    int b = i / ((STEPS + 1) * N);
    int rs = i % ((STEPS + 1) * N);
    int s = rs / N, n = rs % N;
    const float* xp = states + ((size_t)(b * (STEPS + 1) + s)) * NDIM + n * ND;
    float x[8];
#pragma unroll
    for (int k = 0; k < 8; k++) x[k] = xp[k];
    float acc = bo2[0];
#pragma unroll
    for (int j = 0; j < 20; j++) {
        float h = bb1[j];
#pragma unroll
        for (int k = 0; k < 8; k++) h += w1[j * 8 + k] * x[k];
        h = fmaxf(h, 0.f);
        acc += w2[j] * h;
    }
    out[((size_t)(b * N + n)) * (STEPS + 1) + s] = acc;
}

extern "C" void kernel_launch(void* const* d_in, const int* in_sizes, int n_in,
                              void* d_out, int out_size, void* d_ws, size_t ws_size,
                              hipStream_t stream) {
    const float* inputs   = (const float*)d_in[0];
    const float* wordvecs = (const float*)d_in[1];
    const int*   edge_u   = (const int*)d_in[2];
    const int*   edge_v   = (const int*)d_in[3];
    // d_in[4], d_in[5] (mat_u, mat_v) are derivable from edge_u/edge_v — unused
    const float* W_in1 = (const float*)d_in[6];
    const float* b_in1 = (const float*)d_in[7];
    const float* W_in2 = (const float*)d_in[8];
    const float* b_in2 = (const float*)d_in[9];
    const float* W_emb = (const float*)d_in[10];
    const float* b_emb = (const float*)d_in[11];
    const float* rel_mats = (const float*)d_in[12];
    const float* W_ih = (const float*)d_in[13];
    const float* W_hh = (const float*)d_in[14];
    const float* b_ih = (const float*)d_in[15];
    const float* b_hh = (const float*)d_in[16];
    const float* W_o1 = (const float*)d_in[17];
    const float* b_o1 = (const float*)d_in[18];
    const float* W_o2 = (const float*)d_in[19];
    const float* b_o2 = (const float*)d_in[20];
    float* out = (float*)d_out;

    char* ws = (char*)d_ws;
    size_t off = 0;
    auto alloc = [&](size_t bytes) -> void* {
        void* p = ws + off;
        off = (off + bytes + 255) & ~(size_t)255;
        return p;
    };
    int* counts   = (int*)alloc(2048 * 4);
    int* ptr      = (int*)alloc(2048 * 4);
    int* su       = (int*)alloc((size_t)T * E * 4);
    int* sv       = (int*)alloc((size_t)T * E * 4);
    float* norms  = (float*)alloc((size_t)NDIM * 4);
    float* Ab     = (float*)alloc((size_t)B * H1 * 4);
    float* Wvb    = (float*)alloc((size_t)N * H1 * 4);
    float* embs   = (float*)alloc((size_t)N * EMB * 4);
    float* Ahat   = (float*)alloc((size_t)N * RC * 4);
    float* wbuf   = (float*)alloc((size_t)T * E * 64 * 4);
    float* states = (float*)alloc((size_t)B * (STEPS + 1) * NDIM * 4);

    hipMemsetAsync(counts, 0, 2048 * 4, stream);
    k_hist<<<(T * E + 255) / 256, 256, 0, stream>>>(edge_u, counts);
    k_scan<<<1, 1024, 0, stream>>>(counts, ptr);
    k_scatter<<<(T * N) / 4, 256, 0, stream>>>(edge_u, edge_v, ptr, su, sv);

    k_A<<<dim3(H1 / 4, B), 256, 0, stream>>>(inputs, W_in1, Ab);
    k_Wv<<<N * 64 / 4, 256, 0, stream>>>(wordvecs, W_in1, Wvb);
    k_embs<<<N * 64 / 256, 256, 0, stream>>>(wordvecs, W_emb, b_emb, embs);
    k_inputnet<<<B * N / 4, 256, 0, stream>>>(Ab, Wvb, b_in1, W_in2, b_in2, states);

    for (int t = 0; t < T; t++) {
        k_ahat<<<dim3((RC + 255) / 256, N / 8), 256, 0, stream>>>(
            embs, rel_mats + (size_t)t * EMB * RC, Ahat);
        k_weights<<<E / 4, 256, 0, stream>>>(su, sv, embs, Ahat, wbuf, t * E);
    }
    k_norms<<<N / 4, 256, 0, stream>>>(ptr, counts, wbuf, norms);
    k_scale<<<T * E * 64 / 256, 256, 0, stream>>>(sv, wbuf, norms);

    for (int s = 0; s < STEPS; s++)
        k_step<<<N, 256, 0, stream>>>(ptr, counts, sv, wbuf, states,
                                      W_ih, W_hh, b_ih, b_hh, s);

    k_out<<<B * (STEPS + 1) * N / 256, 256, 0, stream>>>(
        states, W_o1, b_o1, W_o2, b_o2, out);
}

// Round 3
// 355.795 us; speedup vs baseline: 1.1650x; 1.1650x over previous
//
#include <hip/hip_runtime.h>
#include <math.h>

constexpr int B = 32, N = 1024, ND = 8, FEAT = 2048, WVD = 300;
constexpr int E = 20000, T = 2, STEPS = 5;
constexpr int NDIM = N * ND;            // 8192
constexpr int H1 = 512;
constexpr int W1C = FEAT + WVD;         // 2348
constexpr int EMB = 50;
constexpr int RC = EMB * ND * ND;       // 3200
constexpr int SROW = (STEPS + 1) * NDIM; // per-batch stride in states
constexpr int SEG = 16;
constexpr int SEGLEN = E / SEG;         // 1250 (NOT a multiple of 64 — guard!)

// ---------------- CSR build (segmented, deterministic) ----------------
// one wave per (t,u,seg): count matches in segment
__global__ void k_seghist(const int* eu, int* segcnt) {
    int wid = (blockIdx.x * 256 + threadIdx.x) >> 6;
    int lane = threadIdx.x & 63;
    int t = wid >> 14;                 // N*SEG = 16384 waves per type
    int u = (wid >> 4) & (N - 1);
    int seg = wid & (SEG - 1);
    const int* eut = eu + t * E;
    int e0 = seg * SEGLEN, e1 = e0 + SEGLEN;
    int cnt = 0;
    for (int c = e0; c < e1; c += 64) {
        int e = c + lane;
        bool ok = (e < e1) && (eut[e] == u);
        unsigned long long m = __ballot(ok);
        cnt += __popcll(m);
    }
    if (lane == 0) segcnt[wid] = cnt;
}

// per-row exclusive scan over SEG segments; also emit row totals (counts)
__global__ void k_segscan(const int* segcnt, int* segoff, int* counts) {
    int row = blockIdx.x * 256 + threadIdx.x;  // 2048 rows
    const int* src = segcnt + row * SEG;
    int* dst = segoff + row * SEG;
    int acc = 0;
#pragma unroll
    for (int s = 0; s < SEG; s++) {
        dst[s] = acc;
        acc += src[s];
    }
    counts[row] = acc;
}

__global__ void k_scan(const int* counts, int* ptr) {
    __shared__ int s0[2048], s1[2048];
    int tid = threadIdx.x;
    s0[tid] = counts[tid];
    s0[tid + 1024] = counts[tid + 1024];
    __syncthreads();
    int* src = s0; int* dst = s1;
    for (int st = 1; st < 2048; st <<= 1) {
        for (int j = tid; j < 2048; j += 1024)
            dst[j] = src[j] + (j >= st ? src[j - st] : 0);
        __syncthreads();
        int* tmp = src; src = dst; dst = tmp;
    }
    ptr[tid] = tid ? src[tid - 1] : 0;
    ptr[tid + 1024] = src[tid + 1023];
}

// one wave per (t,u,seg): ballot-rank scatter within segment (deterministic,
// same global ordering as a full ascending-e scan)
__global__ void k_scatter2(const int* eu, const int* ev, const int* ptr,
                           const int* segoff, int* su, int* sv) {
    int wid = (blockIdx.x * 256 + threadIdx.x) >> 6;
    int lane = threadIdx.x & 63;
    int t = wid >> 14;
    int u = (wid >> 4) & (N - 1);
    int seg = wid & (SEG - 1);
    const int* eut = eu + t * E;
    const int* evt = ev + t * E;
    int row = t * N + u;
    int base = ptr[row] + segoff[row * SEG + seg];
    int e0 = seg * SEGLEN, e1 = e0 + SEGLEN;
    int cnt = 0;
    for (int c = e0; c < e1; c += 64) {
        int e = c + lane;
        bool ok = (e < e1) && (eut[e] == u);
        unsigned long long m = __ballot(ok);
        if (ok) {
            int rank = __popcll(m & ((1ull << lane) - 1));
            int pos = base + cnt + rank;
            su[pos] = u;
            sv[pos] = evt[e];
        }
        cnt += __popcll(m);
    }
}

// ---------------- inputnet ----------------
// A[b,c] = inputs[b,:2048] . W_in1[c,:2048]
__global__ void k_A(const float* inp, const float* W1, float* Ab) {
    int lane = threadIdx.x & 63;
    int w = threadIdx.x >> 6;
    int c = blockIdx.x * 4 + w;
    int b = blockIdx.y;
    const float* xr = inp + (size_t)b * FEAT;
    const float* wr = W1 + (size_t)c * W1C;
    float acc = 0.f;
#pragma unroll
    for (int i = 0; i < FEAT / 64; i++) {
        int k = i * 64 + lane;
        acc += xr[k] * wr[k];
    }
    for (int m = 32; m; m >>= 1) acc += __shfl_xor(acc, m, 64);
    if (lane == 0) Ab[b * H1 + c] = acc;
}

// Wv[n,c] = wordvecs[n,:300] . W_in1[c,2048:2348]   (wave computes 8 c's)
__global__ void k_Wv(const float* wv, const float* W1, float* Wvb) {
    int gw = (blockIdx.x * 256 + threadIdx.x) >> 6;
    int lane = threadIdx.x & 63;
    int n = gw >> 6;
    int c0 = (gw & 63) * 8;
    const float* xr = wv + (size_t)n * WVD;
    float acc[8] = {};
    for (int i = 0; i < 5; i++) {
        int k = i * 64 + lane;
        if (k < WVD) {
            float x = xr[k];
#pragma unroll
            for (int j = 0; j < 8; j++)
                acc[j] += x * W1[(size_t)(c0 + j) * W1C + FEAT + k];
        }
    }
#pragma unroll
    for (int j = 0; j < 8; j++)
        for (int m = 32; m; m >>= 1) acc[j] += __shfl_xor(acc[j], m, 64);
    if (lane == 0) {
#pragma unroll
        for (int j = 0; j < 8; j++) Wvb[n * H1 + c0 + j] = acc[j];
    }
}

// hidden0 = (relu(A[b]+Wv[n]+b1) @ W_in2^T + b2) -> states[:,0,:]
__global__ void k_inputnet(const float* Ab, const float* Wvb, const float* b1,
                           const float* W2, const float* b2, float* states) {
    int gw = (blockIdx.x * 256 + threadIdx.x) >> 6;
    int lane = threadIdx.x & 63;
    int b = gw >> 10, n = gw & (N - 1);
    const float* ar = Ab + b * H1;
    const float* vr = Wvb + n * H1;
    float acc[8] = {};
#pragma unroll
    for (int i = 0; i < H1 / 64; i++) {
        int c = i * 64 + lane;
        float t = ar[c] + vr[c] + b1[c];
        t = fmaxf(t, 0.f);
#pragma unroll
        for (int ki = 0; ki < 8; ki++) acc[ki] += t * W2[ki * H1 + c];
    }
#pragma unroll
    for (int ki = 0; ki < 8; ki++)
        for (int m = 32; m; m >>= 1) acc[ki] += __shfl_xor(acc[ki], m, 64);
    if (lane == 0) {
        float* o = states + (size_t)b * SROW + n * ND;
#pragma unroll
        for (int ki = 0; ki < 8; ki++) o[ki] = acc[ki] + b2[ki];
    }
}

// ---------------- relnet ----------------
__global__ void k_embs(const float* wv, const float* We, const float* be,
                       float* embs) {
    int i = blockIdx.x * 256 + threadIdx.x;
    int n = i >> 6, c = i & 63;
    if (c >= EMB) return;
    const float* xr = wv + (size_t)n * WVD;
    const float* wr = We + (size_t)c * WVD;
    float acc = be[c];
    for (int k = 0; k < WVD; k++) acc += xr[k] * wr[k];
    embs[n * EMB + c] = acc;
}

// Ahat[n, d*64+k] = sum_c embs[n,c] * RM[c, d*64+k]
__global__ void k_ahat(const float* embs, const float* RM, float* Ahat) {
    __shared__ float el[8][EMB];
    int tx = threadIdx.x;
    int n0 = blockIdx.y * 8;
    for (int i = tx; i < 8 * EMB; i += 256)
        el[i / EMB][i % EMB] = embs[(n0 + i / EMB) * EMB + i % EMB];
    __syncthreads();
    int m = blockIdx.x * 256 + tx;
    if (m >= RC) return;
    float acc[8] = {};
    for (int c = 0; c < EMB; c++) {
        float r = RM[(size_t)c * RC + m];
#pragma unroll
        for (int j = 0; j < 8; j++) acc[j] += el[j][c] * r;
    }
#pragma unroll
    for (int j = 0; j < 8; j++) Ahat[(size_t)(n0 + j) * RC + m] = acc[j];
}

// w[slot,k] = sum_d embs[v,d] * Ahat[u, d*64+k]   (one wave per edge slot)
__global__ void k_weights(const int* su, const int* sv, const float* embs,
                          const float* Ahat, float* wbuf, int slot0) {
    int wi = (blockIdx.x * 256 + threadIdx.x) >> 6;
    int k = threadIdx.x & 63;
    if (wi >= E) return;
    int slot = slot0 + wi;
    int u = su[slot], v = sv[slot];
    const float* ar = Ahat + (size_t)u * RC + k;
    const float* vr = embs + (size_t)v * EMB;
    float acc = 0.f;
#pragma unroll 10
    for (int d = 0; d < EMB; d++) acc += vr[d] * ar[d * 64];
    wbuf[(size_t)slot * 64 + k] = acc;
}

// norms[u*8+ki] = sqrt(sum over u's edges, kj of w^2); 0 -> 1  (deterministic)
__global__ void k_norms(const int* ptr, const int* counts, const float* wbuf,
                        float* norms) {
    int u = (blockIdx.x * 256 + threadIdx.x) >> 6;
    int lane = threadIdx.x & 63;
    int ki = lane >> 3, kj = lane & 7;
    float acc = 0.f;
    for (int t = 0; t < T; t++) {
        int base = ptr[t * N + u], c = counts[t * N + u];
        for (int i = 0; i < c; i++) {
            float x = wbuf[(size_t)(base + i) * 64 + lane];
            acc += x * x;
        }
    }
    acc += __shfl_xor(acc, 1, 64);
    acc += __shfl_xor(acc, 2, 64);
    acc += __shfl_xor(acc, 4, 64);
    if (kj == 0) {
        float nv = sqrtf(acc);
        if (nv == 0.f) nv = 1.f;
        norms[u * ND + ki] = nv;
    }
}

// w[slot, ki*8+kj] /= norms[v*8+kj]
__global__ void k_scale(const int* sv, float* wbuf, const float* norms) {
    int idx = blockIdx.x * 256 + threadIdx.x;
    int slot = idx >> 6, k = idx & 63;
    int v = sv[slot];
    wbuf[idx] = wbuf[idx] / norms[v * ND + (k & 7)];
}

// ---------------- propagation step: x = tanh(h @ P^T) fused with GRU ----------------
__global__ void k_step(const int* ptr, const int* counts, const int* sv,
                       const float* wbuf, float* states,
                       const float* W_ih, const float* W_hh,
                       const float* b_ih, const float* b_hh, int s) {
    __shared__ float wl[4][64];
    __shared__ int vl[4];
    __shared__ float xs[B][ND + 1];
    __shared__ float hsm[B][ND + 1];
    __shared__ float wih[24 * 8], whh[24 * 8];
    int tid = threadIdx.x;
    int u = blockIdx.x;
    int b = tid >> 3, ki = tid & 7;
    if (tid < 192) { wih[tid] = W_ih[tid]; whh[tid] = W_hh[tid]; }
    const float* hrow = states + ((size_t)(b * (STEPS + 1) + s)) * NDIM;
    float acc = 0.f;
    for (int t = 0; t < T; t++) {
        int base = ptr[t * N + u], cnt = counts[t * N + u];
        for (int c0 = 0; c0 < cnt; c0 += 4) {
            int nb = min(4, cnt - c0);
            __syncthreads();
            if (tid < nb * 64)
                wl[tid >> 6][tid & 63] =
                    wbuf[(size_t)(base + c0 + (tid >> 6)) * 64 + (tid & 63)];
            if (tid < nb) vl[tid] = sv[base + c0 + tid];
            __syncthreads();
            for (int j = 0; j < nb; j++) {
                int v = vl[j];
                const float4 h0 = *(const float4*)(hrow + v * ND);
                const float4 h1 = *(const float4*)(hrow + v * ND + 4);
                const float* wj = &wl[j][ki * 8];
                acc += h0.x * wj[0] + h0.y * wj[1] + h0.z * wj[2] + h0.w * wj[3]
                     + h1.x * wj[4] + h1.y * wj[5] + h1.z * wj[6] + h1.w * wj[7];
            }
        }
    }
    float xv = tanhf(acc);
    float hown = hrow[u * ND + ki];
    xs[b][ki] = xv;
    hsm[b][ki] = hown;
    __syncthreads();
    float gr = b_ih[ki], gz = b_ih[8 + ki], gn = b_ih[16 + ki];
    float hr = b_hh[ki], hz = b_hh[8 + ki], hn = b_hh[16 + ki];
#pragma unroll
    for (int j = 0; j < 8; j++) {
        float xj = xs[b][j], hj = hsm[b][j];
        gr += wih[ki * 8 + j] * xj;
        gz += wih[(8 + ki) * 8 + j] * xj;
        gn += wih[(16 + ki) * 8 + j] * xj;
        hr += whh[ki * 8 + j] * hj;
        hz += whh[(8 + ki) * 8 + j] * hj;
        hn += whh[(16 + ki) * 8 + j] * hj;
    }
    float r = 1.f / (1.f + expf(-(gr + hr)));
    float z = 1.f / (1.f + expf(-(gz + hz)));
    float nn = tanhf(gn + r * hn);
    float hnew = (1.f - z) * nn + z * hown;
    states[((size_t)(b * (STEPS + 1) + s + 1)) * NDIM + u * ND + ki] = hnew;
}

// ---------------- outnet ----------------
__global__ void k_out(const float* states, const float* Wo1, const float* bo1,
                      const float* Wo2, const float* bo2, float* out) {
    __shared__ float w1[160], bb1[20], w2[20];
    int tid = threadIdx.x;
    if (tid < 160) w1[tid] = Wo1[tid];
    if (tid < 20) { bb1[tid] = bo1[tid]; w2[tid] = Wo2[tid]; }
    __syncthreads();
    int i = blockIdx.x * 256 + tid;
    int b = i / ((STEPS + 1) * N);
    int rs = i % ((STEPS + 1) * N);
    int s = rs / N, n = rs % N;
    const float* xp = states + ((size_t)(b * (STEPS + 1) + s)) * NDIM + n * ND;
    float x[8];
#pragma unroll
    for (int k = 0; k < 8; k++) x[k] = xp[k];
    float acc = bo2[0];
#pragma unroll
    for (int j = 0; j < 20; j++) {
        float h = bb1[j];
#pragma unroll
        for (int k = 0; k < 8; k++) h += w1[j * 8 + k] * x[k];
        h = fmaxf(h, 0.f);
        acc += w2[j] * h;
    }
    out[((size_t)(b * N + n)) * (STEPS + 1) + s] = acc;
}

extern "C" void kernel_launch(void* const* d_in, const int* in_sizes, int n_in,
                              void* d_out, int out_size, void* d_ws, size_t ws_size,
                              hipStream_t stream) {
    const float* inputs   = (const float*)d_in[0];
    const float* wordvecs = (const float*)d_in[1];
    const int*   edge_u   = (const int*)d_in[2];
    const int*   edge_v   = (const int*)d_in[3];
    const float* W_in1 = (const float*)d_in[6];
    const float* b_in1 = (const float*)d_in[7];
    const float* W_in2 = (const float*)d_in[8];
    const float* b_in2 = (const float*)d_in[9];
    const float* W_emb = (const float*)d_in[10];
    const float* b_emb = (const float*)d_in[11];
    const float* rel_mats = (const float*)d_in[12];
    const float* W_ih = (const float*)d_in[13];
    const float* W_hh = (const float*)d_in[14];
    const float* b_ih = (const float*)d_in[15];
    const float* b_hh = (const float*)d_in[16];
    const float* W_o1 = (const float*)d_in[17];
    const float* b_o1 = (const float*)d_in[18];
    const float* W_o2 = (const float*)d_in[19];
    const float* b_o2 = (const float*)d_in[20];
    float* out = (float*)d_out;

    char* ws = (char*)d_ws;
    size_t off = 0;
    auto alloc = [&](size_t bytes) -> void* {
        void* p = ws + off;
        off = (off + bytes + 255) & ~(size_t)255;
        return p;
    };
    int* segcnt   = (int*)alloc((size_t)T * N * SEG * 4);
    int* segoff   = (int*)alloc((size_t)T * N * SEG * 4);
    int* counts   = (int*)alloc(2048 * 4);
    int* ptr      = (int*)alloc(2048 * 4);
    int* su       = (int*)alloc((size_t)T * E * 4);
    int* sv       = (int*)alloc((size_t)T * E * 4);
    float* norms  = (float*)alloc((size_t)NDIM * 4);
    float* Ab     = (float*)alloc((size_t)B * H1 * 4);
    float* Wvb    = (float*)alloc((size_t)N * H1 * 4);
    float* embs   = (float*)alloc((size_t)N * EMB * 4);
    float* Ahat   = (float*)alloc((size_t)N * RC * 4);
    float* wbuf   = (float*)alloc((size_t)T * E * 64 * 4);
    float* states = (float*)alloc((size_t)B * (STEPS + 1) * NDIM * 4);

    k_seghist<<<T * N * SEG / 4, 256, 0, stream>>>(edge_u, segcnt);
    k_segscan<<<T * N / 256, 256, 0, stream>>>(segcnt, segoff, counts);
    k_scan<<<1, 1024, 0, stream>>>(counts, ptr);
    k_scatter2<<<T * N * SEG / 4, 256, 0, stream>>>(edge_u, edge_v, ptr, segoff, su, sv);

    k_A<<<dim3(H1 / 4, B), 256, 0, stream>>>(inputs, W_in1, Ab);
    k_Wv<<<N * 64 / 4, 256, 0, stream>>>(wordvecs, W_in1, Wvb);
    k_embs<<<N * 64 / 256, 256, 0, stream>>>(wordvecs, W_emb, b_emb, embs);
    k_inputnet<<<B * N / 4, 256, 0, stream>>>(Ab, Wvb, b_in1, W_in2, b_in2, states);

    for (int t = 0; t < T; t++) {
        k_ahat<<<dim3((RC + 255) / 256, N / 8), 256, 0, stream>>>(
            embs, rel_mats + (size_t)t * EMB * RC, Ahat);
        k_weights<<<E / 4, 256, 0, stream>>>(su, sv, embs, Ahat, wbuf, t * E);
    }
    k_norms<<<N / 4, 256, 0, stream>>>(ptr, counts, wbuf, norms);
    k_scale<<<T * E * 64 / 256, 256, 0, stream>>>(sv, wbuf, norms);

    for (int s = 0; s < STEPS; s++)
        k_step<<<N, 256, 0, stream>>>(ptr, counts, sv, wbuf, states,
                                      W_ih, W_hh, b_ih, b_hh, s);

    k_out<<<B * (STEPS + 1) * N / 256, 256, 0, stream>>>(
        states, W_o1, b_o1, W_o2, b_o2, out);
}

// Round 4
// 332.280 us; speedup vs baseline: 1.2475x; 1.0708x over previous
//
#include <hip/hip_runtime.h>
#include <math.h>

constexpr int B = 32, N = 1024, ND = 8, FEAT = 2048, WVD = 300;
constexpr int E = 20000, T = 2, STEPS = 5;
constexpr int NDIM = N * ND;            // 8192
constexpr int H1 = 512;
constexpr int W1C = FEAT + WVD;         // 2348
constexpr int EMB = 50;
constexpr int RC = EMB * ND * ND;       // 3200
constexpr int SEG = 16;
constexpr int SEGLEN = E / SEG;         // 1250 (NOT a multiple of 64 — guard!)
constexpr int GRP = 8;

// ---------------- CSR build (segmented, deterministic) ----------------
__global__ void k_seghist(const int* eu, int* segcnt) {
    int wid = (blockIdx.x * 256 + threadIdx.x) >> 6;
    int lane = threadIdx.x & 63;
    int t = wid >> 14;
    int u = (wid >> 4) & (N - 1);
    int seg = wid & (SEG - 1);
    const int* eut = eu + t * E;
    int e0 = seg * SEGLEN, e1 = e0 + SEGLEN;
    int cnt = 0;
    for (int c = e0; c < e1; c += 64) {
        int e = c + lane;
        bool ok = (e < e1) && (eut[e] == u);
        unsigned long long m = __ballot(ok);
        cnt += __popcll(m);
    }
    if (lane == 0) segcnt[wid] = cnt;
}

__global__ void k_segscan(const int* segcnt, int* segoff, int* counts) {
    int row = blockIdx.x * 256 + threadIdx.x;
    const int* src = segcnt + row * SEG;
    int* dst = segoff + row * SEG;
    int acc = 0;
#pragma unroll
    for (int s = 0; s < SEG; s++) {
        dst[s] = acc;
        acc += src[s];
    }
    counts[row] = acc;
}

__global__ void k_scan(const int* counts, int* ptr) {
    __shared__ int s0[2048], s1[2048];
    int tid = threadIdx.x;
    s0[tid] = counts[tid];
    s0[tid + 1024] = counts[tid + 1024];
    __syncthreads();
    int* src = s0; int* dst = s1;
    for (int st = 1; st < 2048; st <<= 1) {
        for (int j = tid; j < 2048; j += 1024)
            dst[j] = src[j] + (j >= st ? src[j - st] : 0);
        __syncthreads();
        int* tmp = src; src = dst; dst = tmp;
    }
    ptr[tid] = tid ? src[tid - 1] : 0;
    ptr[tid + 1024] = src[tid + 1023];
}

__global__ void k_scatter2(const int* eu, const int* ev, const int* ptr,
                           const int* segoff, int* su, int* sv) {
    int wid = (blockIdx.x * 256 + threadIdx.x) >> 6;
    int lane = threadIdx.x & 63;
    int t = wid >> 14;
    int u = (wid >> 4) & (N - 1);
    int seg = wid & (SEG - 1);
    const int* eut = eu + t * E;
    const int* evt = ev + t * E;
    int row = t * N + u;
    int base = ptr[row] + segoff[row * SEG + seg];
    int e0 = seg * SEGLEN, e1 = e0 + SEGLEN;
    int cnt = 0;
    for (int c = e0; c < e1; c += 64) {
        int e = c + lane;
        bool ok = (e < e1) && (eut[e] == u);
        unsigned long long m = __ballot(ok);
        if (ok) {
            int rank = __popcll(m & ((1ull << lane) - 1));
            int pos = base + cnt + rank;
            su[pos] = u;
            sv[pos] = evt[e];
        }
        cnt += __popcll(m);
    }
}

// ---------------- inputnet ----------------
__global__ void k_A(const float* inp, const float* W1, float* Ab) {
    int lane = threadIdx.x & 63;
    int w = threadIdx.x >> 6;
    int c = blockIdx.x * 4 + w;
    int b = blockIdx.y;
    const float* xr = inp + (size_t)b * FEAT;
    const float* wr = W1 + (size_t)c * W1C;
    float acc = 0.f;
#pragma unroll
    for (int i = 0; i < FEAT / 64; i++) {
        int k = i * 64 + lane;
        acc += xr[k] * wr[k];
    }
    for (int m = 32; m; m >>= 1) acc += __shfl_xor(acc, m, 64);
    if (lane == 0) Ab[b * H1 + c] = acc;
}

// transpose W1[:,2048:2348] -> W1T[300][512]
__global__ void k_w1t(const float* W1, float* W1T) {
    __shared__ float tile[32][33];
    int tid = threadIdx.x;
    int c0 = blockIdx.x * 32;
    int k0 = blockIdx.y * 32;
    int kl = tid & 31, cl4 = tid >> 5;
#pragma unroll
    for (int p = 0; p < 4; p++) {
        int c = cl4 + p * 8;
        int k = k0 + kl;
        if (k < WVD) tile[c][kl] = W1[(size_t)(c0 + c) * W1C + FEAT + k];
    }
    __syncthreads();
    int cl = tid & 31, kl4 = tid >> 5;
#pragma unroll
    for (int p = 0; p < 4; p++) {
        int kk = kl4 + p * 8;
        int k = k0 + kk;
        if (k < WVD) W1T[(size_t)k * H1 + c0 + cl] = tile[cl][kk];
    }
}

// Wv[n,c] via tiled GEMM on W1T: block = (c-tile 256) x (8 nodes)
__global__ void k_Wv2(const float* wv, const float* W1T, float* Wvb) {
    __shared__ float el[8][WVD];
    int tid = threadIdx.x;
    int n0 = blockIdx.y * 8;
    for (int idx = tid; idx < 8 * WVD; idx += 256)
        el[idx / WVD][idx % WVD] = wv[(size_t)(n0 + idx / WVD) * WVD + idx % WVD];
    __syncthreads();
    int c = blockIdx.x * 256 + tid;
    float acc[8] = {};
    for (int k = 0; k < WVD; k++) {
        float r = W1T[(size_t)k * H1 + c];
#pragma unroll
        for (int j = 0; j < 8; j++) acc[j] += el[j][k] * r;
    }
#pragma unroll
    for (int j = 0; j < 8; j++) Wvb[(size_t)(n0 + j) * H1 + c] = acc[j];
}

// hidden0 = (relu(A[b]+Wv[n]+b1) @ W_in2^T + b2) -> h0[b][n*8+k]
__global__ void k_inputnet(const float* Ab, const float* Wvb, const float* b1,
                           const float* W2, const float* b2, float* h0) {
    int gw = (blockIdx.x * 256 + threadIdx.x) >> 6;
    int lane = threadIdx.x & 63;
    int b = gw >> 10, n = gw & (N - 1);
    const float* ar = Ab + b * H1;
    const float* vr = Wvb + n * H1;
    float acc[8] = {};
#pragma unroll
    for (int i = 0; i < H1 / 64; i++) {
        int c = i * 64 + lane;
        float t = ar[c] + vr[c] + b1[c];
        t = fmaxf(t, 0.f);
#pragma unroll
        for (int ki = 0; ki < 8; ki++) acc[ki] += t * W2[ki * H1 + c];
    }
#pragma unroll
    for (int ki = 0; ki < 8; ki++)
        for (int m = 32; m; m >>= 1) acc[ki] += __shfl_xor(acc[ki], m, 64);
    if (lane == 0) {
        float* o = h0 + (size_t)b * NDIM + n * ND;
#pragma unroll
        for (int ki = 0; ki < 8; ki++) o[ki] = acc[ki] + b2[ki];
    }
}

// h0[b][i] -> sT[i][b]   (64-i x 32-b tiles)
__global__ void k_tr(const float* h0, float* sT) {
    __shared__ float tile[64][33];
    int tid = threadIdx.x;
    int i0 = blockIdx.x * 64;
    int il = tid & 63, bl = tid >> 6;
#pragma unroll
    for (int p = 0; p < 8; p++) {
        int b = bl + p * 4;
        tile[il][b] = h0[(size_t)b * NDIM + i0 + il];
    }
    __syncthreads();
    int bw = tid & 31, iw = tid >> 5;
#pragma unroll
    for (int p = 0; p < 8; p++) {
        int i = iw + p * 8;
        sT[(size_t)(i0 + i) * B + bw] = tile[i][bw];
    }
}

// ---------------- relnet ----------------
__global__ void k_embs(const float* wv, const float* We, const float* be,
                       float* embs) {
    int i = blockIdx.x * 256 + threadIdx.x;
    int n = i >> 6, c = i & 63;
    if (c >= EMB) return;
    const float* xr = wv + (size_t)n * WVD;
    const float* wr = We + (size_t)c * WVD;
    float acc = be[c];
    for (int k = 0; k < WVD; k++) acc += xr[k] * wr[k];
    embs[n * EMB + c] = acc;
}

__global__ void k_ahat(const float* embs, const float* RM, float* Ahat) {
    __shared__ float el[8][EMB];
    int tx = threadIdx.x;
    int n0 = blockIdx.y * 8;
    for (int i = tx; i < 8 * EMB; i += 256)
        el[i / EMB][i % EMB] = embs[(n0 + i / EMB) * EMB + i % EMB];
    __syncthreads();
    int m = blockIdx.x * 256 + tx;
    if (m >= RC) return;
    float acc[8] = {};
    for (int c = 0; c < EMB; c++) {
        float r = RM[(size_t)c * RC + m];
#pragma unroll
        for (int j = 0; j < 8; j++) acc[j] += el[j][c] * r;
    }
#pragma unroll
    for (int j = 0; j < 8; j++) Ahat[(size_t)(n0 + j) * RC + m] = acc[j];
}

// block-per-u: Ahat[u] staged in LDS once; 4 waves round-robin u's edges
__global__ void k_weights2(const int* ptr, const int* counts, const int* sv,
                           const float* embs, const float* Ahat, float* wbuf,
                           int t) {
    __shared__ float AL[RC];   // 12.8 KB
    int tid = threadIdx.x;
    int u = blockIdx.x;
    int base = ptr[t * N + u], cnt = counts[t * N + u];
    for (int idx = tid; idx < RC; idx += 256)
        AL[idx] = Ahat[(size_t)u * RC + idx];
    __syncthreads();
    int wv_ = tid >> 6, k = tid & 63;
    for (int i = wv_; i < cnt; i += 4) {
        int slot = base + i;
        int v = sv[slot];
        const float* vr = embs + v * EMB;
        float acc = 0.f;
#pragma unroll 10
        for (int d = 0; d < EMB; d++) acc += vr[d] * AL[d * 64 + k];
        wbuf[(size_t)slot * 64 + k] = acc;
    }
}

// norms[u*8+ki] = sqrt(sum over u's edges, kj of w^2); 0 -> 1
__global__ void k_norms(const int* ptr, const int* counts, const float* wbuf,
                        float* norms) {
    int u = (blockIdx.x * 256 + threadIdx.x) >> 6;
    int lane = threadIdx.x & 63;
    int ki = lane >> 3, kj = lane & 7;
    float acc = 0.f;
    for (int t = 0; t < T; t++) {
        int base = ptr[t * N + u], c = counts[t * N + u];
        for (int i = 0; i < c; i++) {
            float x = wbuf[(size_t)(base + i) * 64 + lane];
            acc += x * x;
        }
    }
    acc += __shfl_xor(acc, 1, 64);
    acc += __shfl_xor(acc, 2, 64);
    acc += __shfl_xor(acc, 4, 64);
    if (kj == 0) {
        float nv = sqrtf(acc);
        if (nv == 0.f) nv = 1.f;
        norms[u * ND + ki] = nv;
    }
}

__global__ void k_scale(const int* sv, float* wbuf, const float* norms) {
    int idx = blockIdx.x * 256 + threadIdx.x;
    int slot = idx >> 6, k = idx & 63;
    int v = sv[slot];
    wbuf[idx] = wbuf[idx] / norms[v * ND + (k & 7)];
}

// ---------------- propagation step (transposed layout, coalesced) ----------------
// thread (ki = tid>>5, b = tid&31); block per u
__global__ void k_step2(const int* ptr, const int* counts, const int* sv,
                        const float* wbuf, const float* sT_in, float* sT_out,
                        const float* W_ih, const float* W_hh,
                        const float* b_ih, const float* b_hh) {
    __shared__ float wl[GRP][64];
    __shared__ int vl[GRP];
    __shared__ float hvl[GRP][8][32];   // 8 KB; reused as xs/hs for GRU
    __shared__ float wih[192], whh[192];
    int tid = threadIdx.x;
    int u = blockIdx.x;
    int ki = tid >> 5, b = tid & 31;
    if (tid < 192) { wih[tid] = W_ih[tid]; whh[tid] = W_hh[tid]; }
    float hown = sT_in[((size_t)u * 8 + ki) * B + b];
    float acc = 0.f;
    for (int t = 0; t < T; t++) {
        int base = ptr[t * N + u], cnt = counts[t * N + u];
        for (int c0 = 0; c0 < cnt; c0 += GRP) {
            int nb = min(GRP, cnt - c0);
            __syncthreads();
#pragma unroll
            for (int r = 0; r < GRP * 64 / 256; r++) {
                int idx = tid + r * 256;
                int e = idx >> 6;
                wl[e][idx & 63] =
                    (e < nb) ? wbuf[(size_t)(base + c0 + e) * 64 + (idx & 63)] : 0.f;
            }
            if (tid < GRP) vl[tid] = (tid < nb) ? sv[base + c0 + tid] : 0;
            __syncthreads();
            float r0[GRP];
#pragma unroll
            for (int j = 0; j < GRP; j++)
                r0[j] = sT_in[((size_t)vl[j] * 8 + ki) * B + b];
#pragma unroll
            for (int j = 0; j < GRP; j++) hvl[j][ki][b] = r0[j];
            __syncthreads();
#pragma unroll
            for (int j = 0; j < GRP; j++) {
                const float* wj = &wl[j][ki * 8];
                const float* hj = &hvl[j][0][b];
#pragma unroll
                for (int kj = 0; kj < 8; kj++)
                    acc += wj[kj] * hj[kj * 32];
            }
        }
    }
    float xv = tanhf(acc);
    __syncthreads();
    float* xs = &hvl[0][0][0];
    float* hs = &hvl[2][0][0];
    xs[ki * 32 + b] = xv;
    hs[ki * 32 + b] = hown;
    __syncthreads();
    float gr = b_ih[ki], gz = b_ih[8 + ki], gn = b_ih[16 + ki];
    float hr = b_hh[ki], hz = b_hh[8 + ki], hn = b_hh[16 + ki];
#pragma unroll
    for (int j = 0; j < 8; j++) {
        float xj = xs[j * 32 + b], hj = hs[j * 32 + b];
        gr += wih[ki * 8 + j] * xj;
        gz += wih[(8 + ki) * 8 + j] * xj;
        gn += wih[(16 + ki) * 8 + j] * xj;
        hr += whh[ki * 8 + j] * hj;
        hz += whh[(8 + ki) * 8 + j] * hj;
        hn += whh[(16 + ki) * 8 + j] * hj;
    }
    float r = 1.f / (1.f + expf(-(gr + hr)));
    float z = 1.f / (1.f + expf(-(gz + hz)));
    float nn = tanhf(gn + r * hn);
    float hnew = (1.f - z) * nn + z * hown;
    sT_out[((size_t)u * 8 + ki) * B + b] = hnew;
}

// ---------------- outnet (transposed reads) ----------------
// block per n; 192 threads = 6 s x 32 b
__global__ void k_out2(const float* sT, const float* Wo1, const float* bo1,
                       const float* Wo2, const float* bo2, float* out) {
    __shared__ float w1[160], bb1[20], w2[20];
    __shared__ float res[6][33];
    int tid = threadIdx.x;
    int n = blockIdx.x;
    if (tid < 160) w1[tid] = Wo1[tid];
    if (tid < 20) { bb1[tid] = bo1[tid]; w2[tid] = Wo2[tid]; }
    __syncthreads();
    int b = tid & 31, s = tid >> 5;
    float x[8];
#pragma unroll
    for (int k = 0; k < 8; k++)
        x[k] = sT[((size_t)s * NDIM + n * 8 + k) * B + b];
    float acc = bo2[0];
#pragma unroll
    for (int j = 0; j < 20; j++) {
        float h = bb1[j];
#pragma unroll
        for (int k = 0; k < 8; k++) h += w1[j * 8 + k] * x[k];
        h = fmaxf(h, 0.f);
        acc += w2[j] * h;
    }
    res[s][b] = acc;
    __syncthreads();
    int b_w = tid / 6, s_w = tid - b_w * 6;
    out[(size_t)b_w * ((STEPS + 1) * N) + n * (STEPS + 1) + s_w] = res[s_w][b_w];
}

extern "C" void kernel_launch(void* const* d_in, const int* in_sizes, int n_in,
                              void* d_out, int out_size, void* d_ws, size_t ws_size,
                              hipStream_t stream) {
    const float* inputs   = (const float*)d_in[0];
    const float* wordvecs = (const float*)d_in[1];
    const int*   edge_u   = (const int*)d_in[2];
    const int*   edge_v   = (const int*)d_in[3];
    const float* W_in1 = (const float*)d_in[6];
    const float* b_in1 = (const float*)d_in[7];
    const float* W_in2 = (const float*)d_in[8];
    const float* b_in2 = (const float*)d_in[9];
    const float* W_emb = (const float*)d_in[10];
    const float* b_emb = (const float*)d_in[11];
    const float* rel_mats = (const float*)d_in[12];
    const float* W_ih = (const float*)d_in[13];
    const float* W_hh = (const float*)d_in[14];
    const float* b_ih = (const float*)d_in[15];
    const float* b_hh = (const float*)d_in[16];
    const float* W_o1 = (const float*)d_in[17];
    const float* b_o1 = (const float*)d_in[18];
    const float* W_o2 = (const float*)d_in[19];
    const float* b_o2 = (const float*)d_in[20];
    float* out = (float*)d_out;

    char* ws = (char*)d_ws;
    size_t off = 0;
    auto alloc = [&](size_t bytes) -> void* {
        void* p = ws + off;
        off = (off + bytes + 255) & ~(size_t)255;
        return p;
    };
    int* segcnt   = (int*)alloc((size_t)T * N * SEG * 4);
    int* segoff   = (int*)alloc((size_t)T * N * SEG * 4);
    int* counts   = (int*)alloc(2048 * 4);
    int* ptr      = (int*)alloc(2048 * 4);
    int* su       = (int*)alloc((size_t)T * E * 4);
    int* sv       = (int*)alloc((size_t)T * E * 4);
    float* norms  = (float*)alloc((size_t)NDIM * 4);
    float* Ab     = (float*)alloc((size_t)B * H1 * 4);
    float* W1T    = (float*)alloc((size_t)WVD * H1 * 4);
    float* Wvb    = (float*)alloc((size_t)N * H1 * 4);
    float* embs   = (float*)alloc((size_t)N * EMB * 4);
    float* Ahat   = (float*)alloc((size_t)N * RC * 4);
    float* wbuf   = (float*)alloc((size_t)T * E * 64 * 4);
    float* h0     = (float*)alloc((size_t)B * NDIM * 4);
    float* sT     = (float*)alloc((size_t)(STEPS + 1) * NDIM * B * 4);

    k_seghist<<<T * N * SEG / 4, 256, 0, stream>>>(edge_u, segcnt);
    k_segscan<<<T * N / 256, 256, 0, stream>>>(segcnt, segoff, counts);
    k_scan<<<1, 1024, 0, stream>>>(counts, ptr);
    k_scatter2<<<T * N * SEG / 4, 256, 0, stream>>>(edge_u, edge_v, ptr, segoff, su, sv);

    k_A<<<dim3(H1 / 4, B), 256, 0, stream>>>(inputs, W_in1, Ab);
    k_w1t<<<dim3(H1 / 32, (WVD + 31) / 32), 256, 0, stream>>>(W_in1, W1T);
    k_Wv2<<<dim3(H1 / 256, N / 8), 256, 0, stream>>>(wordvecs, W1T, Wvb);
    k_embs<<<N * 64 / 256, 256, 0, stream>>>(wordvecs, W_emb, b_emb, embs);
    k_inputnet<<<B * N / 4, 256, 0, stream>>>(Ab, Wvb, b_in1, W_in2, b_in2, h0);
    k_tr<<<NDIM / 64, 256, 0, stream>>>(h0, sT);

    for (int t = 0; t < T; t++) {
        k_ahat<<<dim3((RC + 255) / 256, N / 8), 256, 0, stream>>>(
            embs, rel_mats + (size_t)t * EMB * RC, Ahat);
        k_weights2<<<N, 256, 0, stream>>>(ptr, counts, sv, embs, Ahat, wbuf, t);
    }
    k_norms<<<N / 4, 256, 0, stream>>>(ptr, counts, wbuf, norms);
    k_scale<<<T * E * 64 / 256, 256, 0, stream>>>(sv, wbuf, norms);

    for (int s = 0; s < STEPS; s++)
        k_step2<<<N, 256, 0, stream>>>(ptr, counts, sv, wbuf,
                                       sT + (size_t)s * NDIM * B,
                                       sT + (size_t)(s + 1) * NDIM * B,
                                       W_ih, W_hh, b_ih, b_hh);

    k_out2<<<N, 192, 0, stream>>>(sT, W_o1, b_o1, W_o2, b_o2, out);
}